// Round 3
// baseline (785.241 us; speedup 1.0000x reference)
//
#include <hip/hip_runtime.h>
#include <hip/hip_cooperative_groups.h>

namespace cg = cooperative_groups;

typedef unsigned short ushort_t;
typedef unsigned int uint_t;
typedef __attribute__((ext_vector_type(8))) short bf16x8;
typedef __attribute__((ext_vector_type(4))) float f32x4;
typedef __attribute__((ext_vector_type(2))) float f32x2;

#define N_NODES 50000
#define N_EDGES 800000
#define BN_EPS 1e-5f

// ws layout (floats): [0 .. 4800000) h buffer   [4800000..4800192) BN stats
//                     [4800192] edge_index dtype flag (1 = int64)
#define OFF_STATS 4800000
#define OFF_FLAG  4800192

// scratch carved out of d_out (ints) — consumed before bn writes out:
#define SC_PAIR    0        // int2[800000]  (eid, src) sorted by dst
#define SC_OFFSETS 1600000  // int[50001]
#define SC_DEG     1650016  // int[50000]
#define SC_RANK    1700032  // int[800000]
#define SC_BSUM    2500032  // int[196]

#define NB_SCAN 196  // ceil(50000/256)
#define MTILE 64
#define NTILES ((N_NODES + MTILE - 1) / MTILE)  // 782

__device__ __forceinline__ ushort_t f2bf(float f) {
    uint_t u = __float_as_uint(f);
    uint_t r = ((u >> 16) & 1u) + 0x7fffu;  // RNE
    return (ushort_t)((u + r) >> 16);
}

// ======================= shared phase bodies (__device__) ===================

__device__ __forceinline__ void dev_hist(const int* __restrict__ ei, int is64,
                                         int* __restrict__ deg,
                                         int* __restrict__ rank,
                                         int gtid, int nth) {
    for (int e = gtid; e < N_EDGES; e += nth) {
        int s, d;
        if (is64) { s = ei[2 * e]; d = ei[2 * N_EDGES + 2 * e]; }
        else      { s = ei[e];     d = ei[N_EDGES + e]; }
        if ((uint_t)s < N_NODES && (uint_t)d < N_NODES)
            rank[e] = atomicAdd(&deg[d], 1);
    }
}

// per-block inclusive scan of a 256-chunk; local-exclusive to offsets, total to bsum
__device__ __forceinline__ void dev_scanA(const int* __restrict__ deg,
                                          int* __restrict__ offsets,
                                          int* __restrict__ bsum,
                                          int bid, int tid, int* sd) {
    const int i = bid * 256 + tid;
    const int v = (i < N_NODES) ? deg[i] : 0;
    sd[tid] = v;
    __syncthreads();
    for (int off = 1; off < 256; off <<= 1) {
        int u = (tid >= off) ? sd[tid - off] : 0;
        __syncthreads();
        sd[tid] += u;
        __syncthreads();
    }
    if (i < N_NODES) offsets[i] = sd[tid] - v;  // block-local exclusive
    if (tid == 255) bsum[bid] = sd[255];
}

// each block rescans bsum (196 ints, cheap) and adds its base
__device__ __forceinline__ void dev_scanB(int* __restrict__ offsets,
                                          const int* __restrict__ bsum,
                                          int bid, int tid, int* sd) {
    const int v = (tid < NB_SCAN) ? bsum[tid] : 0;
    sd[tid] = v;
    __syncthreads();
    for (int off = 1; off < 256; off <<= 1) {
        int u = (tid >= off) ? sd[tid - off] : 0;
        __syncthreads();
        sd[tid] += u;
        __syncthreads();
    }
    const int base = (bid == 0) ? 0 : sd[bid - 1];
    const int i = bid * 256 + tid;
    if (i < N_NODES) offsets[i] += base;
    if (bid == 0 && tid == 0) offsets[N_NODES] = sd[NB_SCAN - 1];
}

__device__ __forceinline__ void dev_scatter(const int* __restrict__ ei, int is64,
                                            const int* __restrict__ offsets,
                                            const int* __restrict__ rank,
                                            int2* __restrict__ pair,
                                            int gtid, int nth) {
    for (int e = gtid; e < N_EDGES; e += nth) {
        int s, d;
        if (is64) { s = ei[2 * e]; d = ei[2 * N_EDGES + 2 * e]; }
        else      { s = ei[e];     d = ei[N_EDGES + e]; }
        if ((uint_t)s < N_NODES && (uint_t)d < N_NODES)
            pair[offsets[d] + rank[e]] = make_int2(e, s);
    }
}

// node_aggr: one wave per node; 16-edge-chunk MFMA projection + in-reg reduce.
// A[m=t][k=q*8+j], C row m=q*4+r col t  [m89 layout]
__device__ __forceinline__ void dev_node_aggr(
    const float* __restrict__ x, const float* __restrict__ ea,
    const float* __restrict__ We, const float* __restrict__ be,
    const int2* __restrict__ pair, const int* __restrict__ offsets,
    float* __restrict__ hbuf, int wav, int nwav) {
    const int lane = threadIdx.x & 63;
    const int q = lane >> 4;
    const int t = lane & 15;

    bf16x8 Bf[6];
    float ben[6];
#pragma unroll
    for (int f = 0; f < 6; ++f) {
        const int n = t + 16 * f;
#pragma unroll
        for (int j = 0; j < 8; ++j) {
            const int k = q * 8 + j;
            Bf[f][j] = (short)f2bf(We[k * 96 + n]);
        }
        ben[f] = be[n];
    }

    for (int n = wav; n < N_NODES; n += nwav) {
        const int off = offsets[n];
        const int deg = offsets[n + 1] - off;

        float part[6];
#pragma unroll
        for (int f = 0; f < 6; ++f) part[f] = 0.f;

        for (int c0 = 0; c0 < deg; c0 += 16) {
            const int rem = deg - c0;
            int eid_t = -1, src_t = -1;
            if (t < rem) {
                const int2 p = pair[off + c0 + t];
                eid_t = p.x;
                src_t = p.y;
            }
            bf16x8 A = {0, 0, 0, 0, 0, 0, 0, 0};
            if (eid_t >= 0) {
                const float* row = ea + (size_t)eid_t * 32 + q * 8;
                f32x4 a0 = *(const f32x4*)(row);
                f32x4 a1 = *(const f32x4*)(row + 4);
#pragma unroll
                for (int j = 0; j < 4; ++j) {
                    A[j] = (short)f2bf(a0[j]);
                    A[4 + j] = (short)f2bf(a1[j]);
                }
            }

            f32x4 acc[6];
#pragma unroll
            for (int f = 0; f < 6; ++f) {
                f32x4 z = {0.f, 0.f, 0.f, 0.f};
                acc[f] = __builtin_amdgcn_mfma_f32_16x16x32_bf16(A, Bf[f], z, 0, 0, 0);
            }

            int s_r[4];
#pragma unroll
            for (int r = 0; r < 4; ++r) s_r[r] = __shfl(src_t, q * 4 + r);

#pragma unroll
            for (int r = 0; r < 4; ++r) {
                const int m = q * 4 + r;
                if (m < rem) {
                    const float* xrow = x + (size_t)s_r[r] * 96;
#pragma unroll
                    for (int f = 0; f < 6; ++f) {
                        float v = acc[f][r] + ben[f] + xrow[t + 16 * f];
                        part[f] += v > 0.f ? v : 0.f;
                    }
                }
            }
        }

#pragma unroll
        for (int f = 0; f < 6; ++f) {
            part[f] += __shfl_xor(part[f], 16);
            part[f] += __shfl_xor(part[f], 32);
        }

        if (q == 0) {
            const float* xn = x + (size_t)n * 96;
            float* hn = hbuf + (size_t)n * 96;
#pragma unroll
            for (int f = 0; f < 6; ++f) {
                const int col = t + 16 * f;
                hn[col] = part[f] + xn[col];
            }
        }
    }
}

// mlp tile: 64 nodes, 256 threads, fp32 register-tiled (proven body)
__device__ __forceinline__ void dev_mlp_tile(
    float* buf, const float* __restrict__ W1g, const float* __restrict__ b1g,
    const float* __restrict__ W2g, const float* __restrict__ b2g,
    float* __restrict__ stats, int n0, float* Ws, float (*hsT)[68]) {
    const int tid = threadIdx.x;
    const int fg = tid & 15;
    const int ng = tid >> 4;

    for (int i = tid; i < 96 * 96 / 4; i += 256)
        ((f32x4*)Ws)[i] = ((const f32x4*)W1g)[i];
    for (int i = tid; i < MTILE * 96 / 4; i += 256) {
        const int base = i * 4;
        const int nn = base / 96, k = base - nn * 96;
        f32x4 v = {0.f, 0.f, 0.f, 0.f};
        if (n0 + nn < N_NODES)
            v = *(const f32x4*)(buf + (size_t)(n0 + nn) * 96 + k);
        hsT[k][nn] = v[0]; hsT[k + 1][nn] = v[1];
        hsT[k + 2][nn] = v[2]; hsT[k + 3][nn] = v[3];
    }
    __syncthreads();

    float acc[4][6];
#pragma unroll
    for (int ff = 0; ff < 6; ++ff) {
        const float b = b1g[6 * fg + ff];
        acc[0][ff] = b; acc[1][ff] = b; acc[2][ff] = b; acc[3][ff] = b;
    }
    for (int k = 0; k < 96; ++k) {
        const f32x4 a = *(const f32x4*)&hsT[k][4 * ng];
        const float* wr = &Ws[k * 96 + 6 * fg];
        const f32x2 w01 = *(const f32x2*)(wr);
        const f32x2 w23 = *(const f32x2*)(wr + 2);
        const f32x2 w45 = *(const f32x2*)(wr + 4);
        const float w[6] = {w01[0], w01[1], w23[0], w23[1], w45[0], w45[1]};
#pragma unroll
        for (int nn = 0; nn < 4; ++nn)
#pragma unroll
            for (int ff = 0; ff < 6; ++ff) acc[nn][ff] += a[nn] * w[ff];
    }
    __syncthreads();

#pragma unroll
    for (int nn = 0; nn < 4; ++nn)
#pragma unroll
        for (int ff = 0; ff < 6; ++ff) {
            float v = acc[nn][ff];
            hsT[6 * fg + ff][4 * ng + nn] = v > 0.f ? v : 0.f;
        }
    for (int i = tid; i < 96 * 96 / 4; i += 256)
        ((f32x4*)Ws)[i] = ((const f32x4*)W2g)[i];
    __syncthreads();

#pragma unroll
    for (int ff = 0; ff < 6; ++ff) {
        const float b = b2g[6 * fg + ff];
        acc[0][ff] = b; acc[1][ff] = b; acc[2][ff] = b; acc[3][ff] = b;
    }
    for (int k = 0; k < 96; ++k) {
        const f32x4 a = *(const f32x4*)&hsT[k][4 * ng];
        const float* wr = &Ws[k * 96 + 6 * fg];
        const f32x2 w01 = *(const f32x2*)(wr);
        const f32x2 w23 = *(const f32x2*)(wr + 2);
        const f32x2 w45 = *(const f32x2*)(wr + 4);
        const float w[6] = {w01[0], w01[1], w23[0], w23[1], w45[0], w45[1]};
#pragma unroll
        for (int nn = 0; nn < 4; ++nn)
#pragma unroll
            for (int ff = 0; ff < 6; ++ff) acc[nn][ff] += a[nn] * w[ff];
    }

#pragma unroll
    for (int nn = 0; nn < 4; ++nn) {
        const int n = n0 + 4 * ng + nn;
        if (n < N_NODES) {
            float* o = buf + (size_t)n * 96 + 6 * fg;
            *(f32x2*)(o)     = (f32x2){acc[nn][0], acc[nn][1]};
            *(f32x2*)(o + 2) = (f32x2){acc[nn][2], acc[nn][3]};
            *(f32x2*)(o + 4) = (f32x2){acc[nn][4], acc[nn][5]};
        }
    }

    __syncthreads();
#pragma unroll
    for (int nn = 0; nn < 4; ++nn)
#pragma unroll
        for (int ff = 0; ff < 6; ++ff)
            hsT[6 * fg + ff][4 * ng + nn] = acc[nn][ff];
    __syncthreads();

    if (tid < 96) {
        int nmax = N_NODES - n0;
        if (nmax > MTILE) nmax = MTILE;
        float s = 0.f, s2 = 0.f;
        for (int n = 0; n < nmax; ++n) {
            const float v = hsT[tid][n];
            s += v; s2 += v * v;
        }
        atomicAdd(&stats[tid], s);
        atomicAdd(&stats[96 + tid], s2);
    }
}

__device__ __forceinline__ void dev_bn(const float* __restrict__ h2,
                                       const float* __restrict__ stats,
                                       const float* __restrict__ gamma,
                                       const float* __restrict__ beta,
                                       float* __restrict__ out,
                                       float* sc, float* sh,
                                       int gtid, int gstride) {
    const int tid = threadIdx.x;
    if (tid < 96) {
        const float inv_n = 1.f / (float)N_NODES;
        const float mean = stats[tid] * inv_n;
        float var = stats[96 + tid] * inv_n - mean * mean;
        var = var > 0.f ? var : 0.f;
        const float s = gamma[tid] * rsqrtf(var + BN_EPS);
        sc[tid] = s;
        sh[tid] = beta[tid] - mean * s;
    }
    __syncthreads();
    const int total4 = N_NODES * 96 / 4;
    for (int i = gtid; i < total4; i += gstride) {
        f32x4 v = ((const f32x4*)h2)[i];
        const int jb = (i * 4) % 96;
#pragma unroll
        for (int c = 0; c < 4; ++c) {
            float u = v[c] * sc[jb + c] + sh[jb + c];
            v[c] = u > 0.f ? u : 0.f;
        }
        ((f32x4*)out)[i] = v;
    }
}

// ======================= fused cooperative kernels ==========================

// K1: zero+detect | hist+rank | scanA | scanB | scatter | node_aggr
__global__ __launch_bounds__(256, 4) void prep_aggr_kernel(
    const float* __restrict__ x, const int* __restrict__ ei,
    const float* __restrict__ ea, const float* __restrict__ We,
    const float* __restrict__ be, float* __restrict__ hbuf,
    float* __restrict__ stats, int* __restrict__ flag,
    int* __restrict__ scratch) {
    cg::grid_group grid = cg::this_grid();
    __shared__ int sd[256];
    __shared__ int s_any;

    int2* pair   = (int2*)(scratch + SC_PAIR);
    int* offsets = scratch + SC_OFFSETS;
    int* deg     = scratch + SC_DEG;
    int* rank    = scratch + SC_RANK;
    int* bsum    = scratch + SC_BSUM;

    const int tid = threadIdx.x;
    const int bid = blockIdx.x;
    const int nth = gridDim.x * 256;
    const int gtid = bid * 256 + tid;

    // Phase 0: zero deg + stats; block 0 detects int64 vs int32
    for (int i = gtid; i < N_NODES; i += nth) deg[i] = 0;
    if (gtid < 256) stats[gtid] = 0.f;
    if (bid == 0) {
        if (tid == 0) s_any = 0;
        __syncthreads();
        int nz = 0;
        for (int j = 0; j < 16; ++j) {
            const int p = 1 + 2 * (tid * 16 + j) * 195;  // odd, <= 1,598,051
            if (ei[p] != 0) nz = 1;
        }
        if (nz) atomicOr(&s_any, 1);
        __syncthreads();
        if (tid == 0) *flag = s_any ? 0 : 1;
    }
    grid.sync();

    const int is64 = *flag;
    dev_hist(ei, is64, deg, rank, gtid, nth);
    grid.sync();

    if (bid < NB_SCAN) dev_scanA(deg, offsets, bsum, bid, tid, sd);
    grid.sync();
    if (bid < NB_SCAN) dev_scanB(offsets, bsum, bid, tid, sd);
    grid.sync();

    dev_scatter(ei, is64, offsets, rank, pair, gtid, nth);
    grid.sync();

    dev_node_aggr(x, ea, We, be, pair, offsets, hbuf,
                  bid * 4 + (tid >> 6), gridDim.x * 4);
}

// K2: persistent mlp over tiles | grid.sync | bn
__global__ __launch_bounds__(256, 2) void mlp_bn_kernel(
    float* buf, const float* __restrict__ W1g, const float* __restrict__ b1g,
    const float* __restrict__ W2g, const float* __restrict__ b2g,
    float* __restrict__ stats, const float* __restrict__ gamma,
    const float* __restrict__ beta, float* __restrict__ out) {
    cg::grid_group grid = cg::this_grid();
    __shared__ float Ws[96 * 96];
    __shared__ float hsT[96][68];
    __shared__ float sc[96], sh[96];

    for (int tile = blockIdx.x; tile < NTILES; tile += gridDim.x) {
        dev_mlp_tile(buf, W1g, b1g, W2g, b2g, stats, tile * MTILE, Ws, hsT);
        __syncthreads();  // stats reads done before next tile rewrites LDS
    }
    grid.sync();

    dev_bn(buf, stats, gamma, beta, out, sc, sh,
           blockIdx.x * 256 + threadIdx.x, gridDim.x * 256);
}

// ======================= fallback standalone kernels ========================

__global__ __launch_bounds__(1024) void detect_kernel(const int* __restrict__ ei,
                                                      int* __restrict__ flag) {
    __shared__ int any_nonzero;
    if (threadIdx.x == 0) any_nonzero = 0;
    __syncthreads();
    int nz = 0;
#pragma unroll
    for (int q = 0; q < 4; ++q) {
        int p = 1 + 2 * (threadIdx.x * 4 + q) * 195;
        if (ei[p] != 0) nz = 1;
    }
    if (nz) atomicOr(&any_nonzero, 1);
    __syncthreads();
    if (threadIdx.x == 0) *flag = any_nonzero ? 0 : 1;
}

__global__ __launch_bounds__(256) void hist_kernel(const int* __restrict__ ei,
                                                   const int* __restrict__ flag,
                                                   int* __restrict__ deg,
                                                   int* __restrict__ rank) {
    dev_hist(ei, *flag, deg, rank, blockIdx.x * 256 + threadIdx.x,
             gridDim.x * 256);
}

__global__ __launch_bounds__(256) void scanA_kernel(const int* __restrict__ deg,
                                                    int* __restrict__ offsets,
                                                    int* __restrict__ bsum) {
    __shared__ int sd[256];
    dev_scanA(deg, offsets, bsum, blockIdx.x, threadIdx.x, sd);
}

__global__ __launch_bounds__(256) void scanB_kernel(int* __restrict__ offsets,
                                                    const int* __restrict__ bsum) {
    __shared__ int sd[256];
    dev_scanB(offsets, bsum, blockIdx.x, threadIdx.x, sd);
}

__global__ __launch_bounds__(256) void scatter_kernel(const int* __restrict__ ei,
                                                      const int* __restrict__ flag,
                                                      const int* __restrict__ offsets,
                                                      const int* __restrict__ rank,
                                                      int2* __restrict__ pair) {
    dev_scatter(ei, *flag, offsets, rank, pair,
                blockIdx.x * 256 + threadIdx.x, gridDim.x * 256);
}

__global__ __launch_bounds__(256) void node_aggr_kernel(
    const float* __restrict__ x, const float* __restrict__ ea,
    const float* __restrict__ We, const float* __restrict__ be,
    const int2* __restrict__ pair, const int* __restrict__ offsets,
    float* __restrict__ hbuf) {
    dev_node_aggr(x, ea, We, be, pair, offsets, hbuf,
                  blockIdx.x * 4 + (threadIdx.x >> 6), gridDim.x * 4);
}

__global__ __launch_bounds__(256) void mlp_kernel(
    float* buf, const float* __restrict__ W1g, const float* __restrict__ b1g,
    const float* __restrict__ W2g, const float* __restrict__ b2g,
    float* __restrict__ stats) {
    __shared__ float Ws[96 * 96];
    __shared__ float hsT[96][68];
    dev_mlp_tile(buf, W1g, b1g, W2g, b2g, stats, blockIdx.x * MTILE, Ws, hsT);
}

__global__ __launch_bounds__(256) void bn_kernel(
    const float* __restrict__ h2, const float* __restrict__ stats,
    const float* __restrict__ gamma, const float* __restrict__ beta,
    float* __restrict__ out) {
    __shared__ float sc[96], sh[96];
    dev_bn(h2, stats, gamma, beta, out, sc, sh,
           blockIdx.x * 256 + threadIdx.x, gridDim.x * 256);
}

// ---------------------------------------------------------------------------
extern "C" void kernel_launch(void* const* d_in, const int* in_sizes, int n_in,
                              void* d_out, int out_size, void* d_ws,
                              size_t ws_size, hipStream_t stream) {
    const float* x     = (const float*)d_in[0];
    const int*   ei    = (const int*)d_in[1];
    const float* ea    = (const float*)d_in[2];
    const float* We    = (const float*)d_in[3];
    const float* be    = (const float*)d_in[4];
    const float* W1    = (const float*)d_in[5];
    const float* b1    = (const float*)d_in[6];
    const float* W2    = (const float*)d_in[7];
    const float* b2    = (const float*)d_in[8];
    const float* gamma = (const float*)d_in[9];
    const float* beta  = (const float*)d_in[10];
    float* out = (float*)d_out;

    float* ws    = (float*)d_ws;
    float* hbuf  = ws;
    float* stats = ws + OFF_STATS;
    int*   flagp = (int*)(ws + OFF_FLAG);

    int*  scratch = (int*)d_out;
    int2* pair    = (int2*)(scratch + SC_PAIR);
    int*  offsets = scratch + SC_OFFSETS;
    int*  deg     = scratch + SC_DEG;
    int*  rank    = scratch + SC_RANK;
    int*  bsum    = scratch + SC_BSUM;

    // cooperative grid sizes (query once; clamped to co-residency targets)
    static int g1 = 0, g2 = 0;
    if (g1 == 0) {
        int b1n = 0, b2n = 0;
        if (hipOccupancyMaxActiveBlocksPerMultiprocessor(
                &b1n, (const void*)prep_aggr_kernel, 256, 0) != hipSuccess ||
            b1n < 1) b1n = 1;
        if (hipOccupancyMaxActiveBlocksPerMultiprocessor(
                &b2n, (const void*)mlp_bn_kernel, 256, 0) != hipSuccess ||
            b2n < 1) b2n = 1;
        g1 = b1n * 256 > 1024 ? 1024 : b1n * 256;  // >=256 >= NB_SCAN blocks
        g2 = b2n * 256 > 512 ? 512 : b2n * 256;
    }

    void* a1[] = {(void*)&x, (void*)&ei, (void*)&ea, (void*)&We, (void*)&be,
                  (void*)&hbuf, (void*)&stats, (void*)&flagp, (void*)&scratch};
    hipError_t e1 = hipLaunchCooperativeKernel(
        (const void*)prep_aggr_kernel, dim3(g1), dim3(256), a1, 0, stream);
    if (e1 != hipSuccess) {
        // fallback: separate-dispatch pipeline (round-2 proven path)
        hipMemsetAsync((void*)stats, 0, 256 * sizeof(float), stream);
        hipMemsetAsync((void*)deg, 0, N_NODES * sizeof(int), stream);
        detect_kernel<<<1, 1024, 0, stream>>>(ei, flagp);
        hist_kernel<<<1024, 256, 0, stream>>>(ei, flagp, deg, rank);
        scanA_kernel<<<NB_SCAN, 256, 0, stream>>>(deg, offsets, bsum);
        scanB_kernel<<<NB_SCAN, 256, 0, stream>>>(offsets, bsum);
        scatter_kernel<<<1024, 256, 0, stream>>>(ei, flagp, offsets, rank, pair);
        node_aggr_kernel<<<1024, 256, 0, stream>>>(x, ea, We, be, pair, offsets,
                                                   hbuf);
    }

    void* a2[] = {(void*)&hbuf, (void*)&W1, (void*)&b1, (void*)&W2, (void*)&b2,
                  (void*)&stats, (void*)&gamma, (void*)&beta, (void*)&out};
    hipError_t e2 = hipLaunchCooperativeKernel(
        (const void*)mlp_bn_kernel, dim3(g2), dim3(256), a2, 0, stream);
    if (e2 != hipSuccess) {
        mlp_kernel<<<NTILES, 256, 0, stream>>>(hbuf, W1, b1, W2, b2, stats);
        bn_kernel<<<1024, 256, 0, stream>>>(hbuf, stats, gamma, beta, out);
    }
}

// Round 4
// 390.039 us; speedup vs baseline: 2.0132x; 2.0132x over previous
//
#include <hip/hip_runtime.h>

typedef unsigned short ushort_t;
typedef unsigned int uint_t;
typedef __attribute__((ext_vector_type(8))) short bf16x8;
typedef __attribute__((ext_vector_type(4))) float f32x4;
typedef __attribute__((ext_vector_type(2))) float f32x2;

#define N_NODES 50000
#define N_EDGES 800000
#define BN_EPS 1e-5f

// ws layout (floats): [0 .. 4800000) h buffer   [4800000..4800192) BN stats
//                     [4800192] edge_index dtype flag (1 = int64)
#define OFF_STATS 4800000
#define OFF_FLAG  4800192

// scratch carved out of d_out (ints) — consumed before bn writes out:
#define SC_PAIR  0        // int2[800000]  (eid, src) sorted by dst
#define SC_LEXCL 1600000  // int[50000]  block-local exclusive prefix of deg
#define SC_DEG   1650016  // int[50000]
#define SC_RANK  1700032  // int[800000]
#define SC_BSUM  2500032  // int[196]    per-256-chunk degree totals

#define NB_SCAN 196  // ceil(50000/256)
#define MTILE 64
#define NTILES ((N_NODES + MTILE - 1) / MTILE)  // 782

__device__ __forceinline__ ushort_t f2bf(float f) {
    uint_t u = __float_as_uint(f);
    uint_t r = ((u >> 16) & 1u) + 0x7fffu;  // RNE
    return (ushort_t)((u + r) >> 16);
}

// ---------------------------------------------------------------------------
// init: zero deg + stats; block 0 detects int64 vs int32 edge_index.
// (replaces 2 memsets + detect dispatch)
// ---------------------------------------------------------------------------
__global__ __launch_bounds__(256) void init_kernel(const int* __restrict__ ei,
                                                   int* __restrict__ flag,
                                                   int* __restrict__ deg,
                                                   float* __restrict__ stats) {
    const int gtid = blockIdx.x * 256 + threadIdx.x;
    const int nth = gridDim.x * 256;
    for (int i = gtid; i < N_NODES; i += nth) deg[i] = 0;
    if (gtid < 256) stats[gtid] = 0.f;
    if (blockIdx.x == 0) {
        __shared__ int s_any;
        if (threadIdx.x == 0) s_any = 0;
        __syncthreads();
        int nz = 0;
#pragma unroll
        for (int j = 0; j < 16; ++j) {
            const int p = 1 + 2 * (threadIdx.x * 16 + j) * 195;  // odd, <1.6M
            if (ei[p] != 0) nz = 1;
        }
        if (nz) atomicOr(&s_any, 1);
        __syncthreads();
        if (threadIdx.x == 0) *flag = s_any ? 0 : 1;
    }
}

// ---------------------------------------------------------------------------
// hist: rank[e] = old deg[dst]++ (rank within dst bucket; scatter needs no
// atomics).
// ---------------------------------------------------------------------------
__global__ __launch_bounds__(256) void hist_kernel(const int* __restrict__ ei,
                                                   const int* __restrict__ flag,
                                                   int* __restrict__ deg,
                                                   int* __restrict__ rank) {
    const int is64 = *flag;
    const int stride = gridDim.x * blockDim.x;
    for (int e = blockIdx.x * blockDim.x + threadIdx.x; e < N_EDGES; e += stride) {
        int s, d;
        if (is64) { s = ei[2 * e]; d = ei[2 * N_EDGES + 2 * e]; }
        else      { s = ei[e];     d = ei[N_EDGES + e]; }
        if ((uint_t)s < N_NODES && (uint_t)d < N_NODES)
            rank[e] = atomicAdd(&deg[d], 1);
    }
}

// ---------------------------------------------------------------------------
// scanA: per-256-chunk scan. lexcl[i] = exclusive prefix within chunk,
// bsum[chunk] = chunk total. Consumers rebuild the 196-entry chunk-base scan
// in LDS (cheap), so no scanB dispatch.
// ---------------------------------------------------------------------------
__global__ __launch_bounds__(256) void scanA_kernel(const int* __restrict__ deg,
                                                    int* __restrict__ lexcl,
                                                    int* __restrict__ bsum) {
    __shared__ int sd[256];
    const int tid = threadIdx.x;
    const int i = blockIdx.x * 256 + tid;
    const int v = (i < N_NODES) ? deg[i] : 0;
    sd[tid] = v;
    __syncthreads();
    for (int off = 1; off < 256; off <<= 1) {
        int u = (tid >= off) ? sd[tid - off] : 0;
        __syncthreads();
        sd[tid] += u;
        __syncthreads();
    }
    if (i < N_NODES) lexcl[i] = sd[tid] - v;
    if (tid == 255) bsum[blockIdx.x] = sd[255];
}

// builds sbase[0..195] (exclusive chunk bases) in LDS; returns total in *tot.
// call with all 256 threads; uses sd[256] workspace.
__device__ __forceinline__ void build_sbase(const int* __restrict__ bsum,
                                            int* sd, int* sbase, int* tot) {
    const int tid = threadIdx.x;
    const int v = (tid < NB_SCAN) ? bsum[tid] : 0;
    sd[tid] = v;
    __syncthreads();
    for (int off = 1; off < 256; off <<= 1) {
        int u = (tid >= off) ? sd[tid - off] : 0;
        __syncthreads();
        sd[tid] += u;
        __syncthreads();
    }
    if (tid < NB_SCAN) sbase[tid] = sd[tid] - v;
    if (tid == NB_SCAN - 1) *tot = sd[tid];
    __syncthreads();
}

// ---------------------------------------------------------------------------
// scatter (atomic-free): pos = sbase[d>>8] + lexcl[d] + rank[e];
// pair[pos] = (eid, src).
// ---------------------------------------------------------------------------
__global__ __launch_bounds__(256) void scatter_kernel(const int* __restrict__ ei,
                                                      const int* __restrict__ flag,
                                                      const int* __restrict__ lexcl,
                                                      const int* __restrict__ bsum,
                                                      const int* __restrict__ rank,
                                                      int2* __restrict__ pair) {
    __shared__ int sd[256];
    __shared__ int sbase[NB_SCAN];
    __shared__ int tot;
    build_sbase(bsum, sd, sbase, &tot);

    const int is64 = *flag;
    const int stride = gridDim.x * blockDim.x;
    for (int e = blockIdx.x * blockDim.x + threadIdx.x; e < N_EDGES; e += stride) {
        int s, d;
        if (is64) { s = ei[2 * e]; d = ei[2 * N_EDGES + 2 * e]; }
        else      { s = ei[e];     d = ei[N_EDGES + e]; }
        if ((uint_t)s < N_NODES && (uint_t)d < N_NODES) {
            const int pos = sbase[d >> 8] + lexcl[d] + rank[e];
            pair[pos] = make_int2(e, s);
        }
    }
}

// ---------------------------------------------------------------------------
// node_aggr: one wave per node (grid-stride). For each 16-edge chunk:
//   proj[16e x 96f] = ea[eids] @ We  via 6x mfma 16x16x32 bf16
//   (A[m=t][k=q*8+j], C row m=q*4+r col t  [m89 layout])
//   part[f] += relu(proj + be + x[src]) over the quad's 4 rows; butterfly
//   across quads; ONE plain store per element. No float atomics.
// ---------------------------------------------------------------------------
__global__ __launch_bounds__(256) void node_aggr_kernel(
    const float* __restrict__ x, const float* __restrict__ ea,
    const float* __restrict__ We, const float* __restrict__ be,
    const int2* __restrict__ pair, const int* __restrict__ lexcl,
    const int* __restrict__ bsum, float* __restrict__ hbuf) {
    __shared__ int sd[256];
    __shared__ int sbase[NB_SCAN];
    __shared__ int tot;
    build_sbase(bsum, sd, sbase, &tot);

    const int lane = threadIdx.x & 63;
    const int q = lane >> 4;
    const int t = lane & 15;
    const int wav = blockIdx.x * 4 + (threadIdx.x >> 6);
    const int nwav = gridDim.x * 4;

    bf16x8 Bf[6];
    float ben[6];
#pragma unroll
    for (int f = 0; f < 6; ++f) {
        const int n = t + 16 * f;
#pragma unroll
        for (int j = 0; j < 8; ++j) {
            const int k = q * 8 + j;
            Bf[f][j] = (short)f2bf(We[k * 96 + n]);
        }
        ben[f] = be[n];
    }

    for (int n = wav; n < N_NODES; n += nwav) {
        const int off = sbase[n >> 8] + lexcl[n];
        const int offn = (n + 1 == N_NODES) ? tot
                         : sbase[(n + 1) >> 8] + lexcl[n + 1];
        const int deg = offn - off;

        float part[6];
#pragma unroll
        for (int f = 0; f < 6; ++f) part[f] = 0.f;

        for (int c0 = 0; c0 < deg; c0 += 16) {
            const int rem = deg - c0;
            int eid_t = -1, src_t = -1;
            if (t < rem) {
                const int2 p = pair[off + c0 + t];
                eid_t = p.x;
                src_t = p.y;
            }
            bf16x8 A = {0, 0, 0, 0, 0, 0, 0, 0};
            if (eid_t >= 0) {
                const float* row = ea + (size_t)eid_t * 32 + q * 8;
                f32x4 a0 = *(const f32x4*)(row);
                f32x4 a1 = *(const f32x4*)(row + 4);
#pragma unroll
                for (int j = 0; j < 4; ++j) {
                    A[j] = (short)f2bf(a0[j]);
                    A[4 + j] = (short)f2bf(a1[j]);
                }
            }

            f32x4 acc[6];
#pragma unroll
            for (int f = 0; f < 6; ++f) {
                f32x4 z = {0.f, 0.f, 0.f, 0.f};
                acc[f] = __builtin_amdgcn_mfma_f32_16x16x32_bf16(A, Bf[f], z, 0, 0, 0);
            }

            int s_r[4];
#pragma unroll
            for (int r = 0; r < 4; ++r) s_r[r] = __shfl(src_t, q * 4 + r);

#pragma unroll
            for (int r = 0; r < 4; ++r) {
                const int m = q * 4 + r;
                if (m < rem) {
                    const float* xrow = x + (size_t)s_r[r] * 96;
#pragma unroll
                    for (int f = 0; f < 6; ++f) {
                        float v = acc[f][r] + ben[f] + xrow[t + 16 * f];
                        part[f] += v > 0.f ? v : 0.f;
                    }
                }
            }
        }

#pragma unroll
        for (int f = 0; f < 6; ++f) {
            part[f] += __shfl_xor(part[f], 16);
            part[f] += __shfl_xor(part[f], 32);
        }

        if (q == 0) {
            const float* xn = x + (size_t)n * 96;
            float* hn = hbuf + (size_t)n * 96;
#pragma unroll
            for (int f = 0; f < 6; ++f) {
                const int col = t + 16 * f;
                hn[col] = part[f] + xn[col];
            }
        }
    }
}

// ---------------------------------------------------------------------------
// mlp v2 (fp32, register-tiled): 64-node tile, 256 threads.
// thread (fg=tid&15, ng=tid>>4): 4 nodes x 6 features, 24 accumulators.
// hsT[k][n] (pad 68), Ws[96*96]; proven round-2 body.
// ---------------------------------------------------------------------------
__global__ __launch_bounds__(256) void mlp_kernel(
    float* buf, const float* __restrict__ W1g, const float* __restrict__ b1g,
    const float* __restrict__ W2g, const float* __restrict__ b2g,
    float* __restrict__ stats) {
    __shared__ float Ws[96 * 96];
    __shared__ float hsT[96][68];

    const int tid = threadIdx.x;
    const int fg = tid & 15;
    const int ng = tid >> 4;
    const int n0 = blockIdx.x * MTILE;

    for (int i = tid; i < 96 * 96 / 4; i += 256)
        ((f32x4*)Ws)[i] = ((const f32x4*)W1g)[i];
    for (int i = tid; i < MTILE * 96 / 4; i += 256) {
        const int base = i * 4;
        const int nn = base / 96, k = base - nn * 96;
        f32x4 v = {0.f, 0.f, 0.f, 0.f};
        if (n0 + nn < N_NODES)
            v = *(const f32x4*)(buf + (size_t)(n0 + nn) * 96 + k);
        hsT[k][nn] = v[0]; hsT[k + 1][nn] = v[1];
        hsT[k + 2][nn] = v[2]; hsT[k + 3][nn] = v[3];
    }
    __syncthreads();

    float acc[4][6];
#pragma unroll
    for (int ff = 0; ff < 6; ++ff) {
        const float b = b1g[6 * fg + ff];
        acc[0][ff] = b; acc[1][ff] = b; acc[2][ff] = b; acc[3][ff] = b;
    }
    for (int k = 0; k < 96; ++k) {
        const f32x4 a = *(const f32x4*)&hsT[k][4 * ng];
        const float* wr = &Ws[k * 96 + 6 * fg];
        const f32x2 w01 = *(const f32x2*)(wr);
        const f32x2 w23 = *(const f32x2*)(wr + 2);
        const f32x2 w45 = *(const f32x2*)(wr + 4);
        const float w[6] = {w01[0], w01[1], w23[0], w23[1], w45[0], w45[1]};
#pragma unroll
        for (int nn = 0; nn < 4; ++nn)
#pragma unroll
            for (int ff = 0; ff < 6; ++ff) acc[nn][ff] += a[nn] * w[ff];
    }
    __syncthreads();

#pragma unroll
    for (int nn = 0; nn < 4; ++nn)
#pragma unroll
        for (int ff = 0; ff < 6; ++ff) {
            float v = acc[nn][ff];
            hsT[6 * fg + ff][4 * ng + nn] = v > 0.f ? v : 0.f;
        }
    for (int i = tid; i < 96 * 96 / 4; i += 256)
        ((f32x4*)Ws)[i] = ((const f32x4*)W2g)[i];
    __syncthreads();

#pragma unroll
    for (int ff = 0; ff < 6; ++ff) {
        const float b = b2g[6 * fg + ff];
        acc[0][ff] = b; acc[1][ff] = b; acc[2][ff] = b; acc[3][ff] = b;
    }
    for (int k = 0; k < 96; ++k) {
        const f32x4 a = *(const f32x4*)&hsT[k][4 * ng];
        const float* wr = &Ws[k * 96 + 6 * fg];
        const f32x2 w01 = *(const f32x2*)(wr);
        const f32x2 w23 = *(const f32x2*)(wr + 2);
        const f32x2 w45 = *(const f32x2*)(wr + 4);
        const float w[6] = {w01[0], w01[1], w23[0], w23[1], w45[0], w45[1]};
#pragma unroll
        for (int nn = 0; nn < 4; ++nn)
#pragma unroll
            for (int ff = 0; ff < 6; ++ff) acc[nn][ff] += a[nn] * w[ff];
    }

#pragma unroll
    for (int nn = 0; nn < 4; ++nn) {
        const int n = n0 + 4 * ng + nn;
        if (n < N_NODES) {
            float* o = buf + (size_t)n * 96 + 6 * fg;
            *(f32x2*)(o)     = (f32x2){acc[nn][0], acc[nn][1]};
            *(f32x2*)(o + 2) = (f32x2){acc[nn][2], acc[nn][3]};
            *(f32x2*)(o + 4) = (f32x2){acc[nn][4], acc[nn][5]};
        }
    }

    __syncthreads();
#pragma unroll
    for (int nn = 0; nn < 4; ++nn)
#pragma unroll
        for (int ff = 0; ff < 6; ++ff)
            hsT[6 * fg + ff][4 * ng + nn] = acc[nn][ff];
    __syncthreads();

    if (tid < 96) {
        int nmax = N_NODES - n0;
        if (nmax > MTILE) nmax = MTILE;
        float s = 0.f, s2 = 0.f;
        for (int n = 0; n < nmax; ++n) {
            const float v = hsT[tid][n];
            s += v; s2 += v * v;
        }
        atomicAdd(&stats[tid], s);
        atomicAdd(&stats[96 + tid], s2);
    }
}

// ---------------------------------------------------------------------------
// bn: finalize + affine + ReLU, float4 streaming.
// ---------------------------------------------------------------------------
__global__ __launch_bounds__(256) void bn_kernel(
    const float* __restrict__ h2, const float* __restrict__ stats,
    const float* __restrict__ gamma, const float* __restrict__ beta,
    float* __restrict__ out) {
    __shared__ float sc[96], sh[96];
    const int tid = threadIdx.x;
    if (tid < 96) {
        const float inv_n = 1.f / (float)N_NODES;
        const float mean = stats[tid] * inv_n;
        float var = stats[96 + tid] * inv_n - mean * mean;
        var = var > 0.f ? var : 0.f;
        const float s = gamma[tid] * rsqrtf(var + BN_EPS);
        sc[tid] = s;
        sh[tid] = beta[tid] - mean * s;
    }
    __syncthreads();
    const int total4 = N_NODES * 96 / 4;
    for (int i = blockIdx.x * blockDim.x + tid; i < total4;
         i += gridDim.x * blockDim.x) {
        f32x4 v = ((const f32x4*)h2)[i];
        const int jb = (i * 4) % 96;
#pragma unroll
        for (int c = 0; c < 4; ++c) {
            float u = v[c] * sc[jb + c] + sh[jb + c];
            v[c] = u > 0.f ? u : 0.f;
        }
        ((f32x4*)out)[i] = v;
    }
}

// ---------------------------------------------------------------------------
extern "C" void kernel_launch(void* const* d_in, const int* in_sizes, int n_in,
                              void* d_out, int out_size, void* d_ws,
                              size_t ws_size, hipStream_t stream) {
    const float* x     = (const float*)d_in[0];
    const int*   ei    = (const int*)d_in[1];
    const float* ea    = (const float*)d_in[2];
    const float* We    = (const float*)d_in[3];
    const float* be    = (const float*)d_in[4];
    const float* W1    = (const float*)d_in[5];
    const float* b1    = (const float*)d_in[6];
    const float* W2    = (const float*)d_in[7];
    const float* b2    = (const float*)d_in[8];
    const float* gamma = (const float*)d_in[9];
    const float* beta  = (const float*)d_in[10];
    float* out = (float*)d_out;

    float* ws    = (float*)d_ws;
    float* hbuf  = ws;
    float* stats = ws + OFF_STATS;
    int*   flagp = (int*)(ws + OFF_FLAG);

    int*  scratch = (int*)d_out;
    int2* pair    = (int2*)(scratch + SC_PAIR);
    int*  lexcl   = scratch + SC_LEXCL;
    int*  deg     = scratch + SC_DEG;
    int*  rank    = scratch + SC_RANK;
    int*  bsum    = scratch + SC_BSUM;

    init_kernel<<<NB_SCAN, 256, 0, stream>>>(ei, flagp, deg, stats);
    hist_kernel<<<1024, 256, 0, stream>>>(ei, flagp, deg, rank);
    scanA_kernel<<<NB_SCAN, 256, 0, stream>>>(deg, lexcl, bsum);
    scatter_kernel<<<1024, 256, 0, stream>>>(ei, flagp, lexcl, bsum, rank, pair);
    node_aggr_kernel<<<2048, 256, 0, stream>>>(x, ea, We, be, pair, lexcl,
                                               bsum, hbuf);
    mlp_kernel<<<NTILES, 256, 0, stream>>>(hbuf, W1, b1, W2, b2, stats);
    bn_kernel<<<1024, 256, 0, stream>>>(hbuf, stats, gamma, beta, out);
}